// Round 1
// baseline (319.033 us; speedup 1.0000x reference)
//
#include <hip/hip_runtime.h>
#include <math.h>

#define N_TOK 2048
#define NDIM 512
#define HEADS 8
#define NUM_KEYS 256
#define DIM_KEY 256
#define TOPK 16
#define QCOLS 4096  // 2*HEADS*DIM_KEY

// ---------------- K1: M[c, p*2048+h*256+k] = sum_d Wq[c, p*2048+h*256+d] * keys[h,k,p,d]
// 16 independent [512,256] = [512x256_d] @ [256_k x 256_d]^T GEMMs (one per (p,h))
__global__ __launch_bounds__(256) void k1_combine(const float* __restrict__ Wq,
                                                  const float* __restrict__ keys,
                                                  float* __restrict__ M) {
    __shared__ float As[16][64];
    __shared__ float Bs[16][64];
    const int ph = blockIdx.z;       // p*8 + h
    const int p = ph >> 3, h = ph & 7;
    const int off = p * 2048 + h * 256;
    const int c0 = blockIdx.x * 64;
    const int k0 = blockIdx.y * 64;
    const int tid = threadIdx.x;
    const int lr = tid >> 2;          // 0..63
    const int ld4 = (tid & 3) * 4;    // 0,4,8,12
    const int tr = tid >> 4, tc = tid & 15;
    float acc[4][4] = {};
    for (int d0 = 0; d0 < DIM_KEY; d0 += 16) {
        float4 av = *reinterpret_cast<const float4*>(&Wq[(size_t)(c0 + lr) * QCOLS + off + d0 + ld4]);
        float4 bv = *reinterpret_cast<const float4*>(&keys[(size_t)((h * 256 + (k0 + lr)) * 2 + p) * 256 + d0 + ld4]);
        __syncthreads();
        As[ld4 + 0][lr] = av.x; As[ld4 + 1][lr] = av.y; As[ld4 + 2][lr] = av.z; As[ld4 + 3][lr] = av.w;
        Bs[ld4 + 0][lr] = bv.x; Bs[ld4 + 1][lr] = bv.y; Bs[ld4 + 2][lr] = bv.z; Bs[ld4 + 3][lr] = bv.w;
        __syncthreads();
        #pragma unroll
        for (int kk = 0; kk < 16; ++kk) {
            float4 a = *reinterpret_cast<const float4*>(&As[kk][tr * 4]);
            float4 b = *reinterpret_cast<const float4*>(&Bs[kk][tc * 4]);
            float aa[4] = {a.x, a.y, a.z, a.w}, bb[4] = {b.x, b.y, b.z, b.w};
            #pragma unroll
            for (int i = 0; i < 4; ++i)
                #pragma unroll
                for (int j = 0; j < 4; ++j) acc[i][j] += aa[i] * bb[j];
        }
    }
    #pragma unroll
    for (int i = 0; i < 4; ++i) {
        float4 o = {acc[i][0], acc[i][1], acc[i][2], acc[i][3]};
        *reinterpret_cast<float4*>(&M[(size_t)(c0 + tr * 4 + i) * QCOLS + off + k0 + tc * 4]) = o;
    }
}

// ---------------- K2: sim[2048,4096] = x[2048,512] @ M[512,4096], fp32 VALU GEMM
__global__ __launch_bounds__(256) void k2_gemm(const float* __restrict__ A,
                                               const float* __restrict__ B,
                                               float* __restrict__ C) {
    __shared__ float As[8][128];
    __shared__ float Bs[8][128];
    const int row0 = blockIdx.x * 128;
    const int col0 = blockIdx.y * 128;
    const int tid = threadIdx.x;
    const int ar = tid >> 1, ak = (tid & 1) * 4;
    const int bk = tid >> 5, bc = (tid & 31) * 4;
    const int tr = tid >> 4, tc = tid & 15;
    float acc[8][8] = {};
    for (int k0 = 0; k0 < NDIM; k0 += 8) {
        float4 av = *reinterpret_cast<const float4*>(&A[(size_t)(row0 + ar) * NDIM + k0 + ak]);
        float4 bv = *reinterpret_cast<const float4*>(&B[(size_t)(k0 + bk) * QCOLS + col0 + bc]);
        __syncthreads();
        As[ak + 0][ar] = av.x; As[ak + 1][ar] = av.y; As[ak + 2][ar] = av.z; As[ak + 3][ar] = av.w;
        *reinterpret_cast<float4*>(&Bs[bk][bc]) = bv;
        __syncthreads();
        #pragma unroll
        for (int kk = 0; kk < 8; ++kk) {
            float a[8], b[8];
            *(float4*)&a[0] = *(const float4*)&As[kk][tr * 8];
            *(float4*)&a[4] = *(const float4*)&As[kk][tr * 8 + 4];
            *(float4*)&b[0] = *(const float4*)&Bs[kk][tc * 8];
            *(float4*)&b[4] = *(const float4*)&Bs[kk][tc * 8 + 4];
            #pragma unroll
            for (int i = 0; i < 8; ++i)
                #pragma unroll
                for (int j = 0; j < 8; ++j) acc[i][j] += a[i] * b[j];
        }
    }
    #pragma unroll
    for (int i = 0; i < 8; ++i) {
        float* cp = &C[(size_t)(row0 + tr * 8 + i) * QCOLS + col0 + tc * 8];
        float4 o0 = {acc[i][0], acc[i][1], acc[i][2], acc[i][3]};
        float4 o1 = {acc[i][4], acc[i][5], acc[i][6], acc[i][7]};
        *(float4*)cp = o0;
        *(float4*)(cp + 4) = o1;
    }
}

// ---------------- K3: per (n,h) wave: top16(p0), top16(p1), combined top16 (stable,
// lower flat index on ties), dots with down_embed, gelu, softmax -> (idx, weight)
__device__ __forceinline__ void argmax_combine(float& v, int& i, float vo, int io) {
    if (vo > v || (vo == v && io < i)) { v = vo; i = io; }
}

__global__ __launch_bounds__(256) void k3_topk(const float* __restrict__ sim,
                                               const float* __restrict__ x,
                                               const float* __restrict__ down,
                                               int* __restrict__ idx_out,
                                               float* __restrict__ w_out) {
    const int tid = threadIdx.x;
    const int lane = tid & 63;
    const int wv = tid >> 6;
    const int pair = blockIdx.x * 4 + wv;  // 0 .. 2048*8-1
    const int n = pair >> 3, h = pair & 7;

    // phase 1: per-p top-16 VALUES (order of indices irrelevant downstream).
    // lane r keeps the round-r (rank-r) value.
    float sxv = 0.f, syv = 0.f;
    #pragma unroll
    for (int p = 0; p < 2; ++p) {
        const float* s = sim + (size_t)n * QCOLS + p * 2048 + h * 256;
        float v[4];
        #pragma unroll
        for (int t = 0; t < 4; ++t) v[t] = s[lane * 4 + t];
        float keep = 0.f;
        #pragma unroll
        for (int r = 0; r < 16; ++r) {
            float mv = v[0]; int mi = lane * 4;
            #pragma unroll
            for (int t = 1; t < 4; ++t) argmax_combine(mv, mi, v[t], lane * 4 + t);
            #pragma unroll
            for (int off = 1; off < 64; off <<= 1) {
                float ov = __shfl_xor(mv, off);
                int oi = __shfl_xor(mi, off);
                argmax_combine(mv, mi, ov, oi);
            }
            if (lane == r) keep = mv;
            #pragma unroll
            for (int t = 0; t < 4; ++t)
                if (lane * 4 + t == mi) v[t] = -INFINITY;
        }
        if (p == 0) sxv = keep; else syv = keep;
    }

    // phase 2: 256 cartesian sums, top-16 with flat index; ties -> lower flat index
    float cv[4];
    #pragma unroll
    for (int t = 0; t < 4; ++t) {
        int f = lane * 4 + t;
        cv[t] = __shfl(sxv, f >> 4) + __shfl(syv, f & 15);
    }
    float scores[16]; int fr[16];
    #pragma unroll
    for (int r = 0; r < 16; ++r) {
        float mv = cv[0]; int mi = lane * 4;
        #pragma unroll
        for (int t = 1; t < 4; ++t) argmax_combine(mv, mi, cv[t], lane * 4 + t);
        #pragma unroll
        for (int off = 1; off < 64; off <<= 1) {
            float ov = __shfl_xor(mv, off);
            int oi = __shfl_xor(mi, off);
            argmax_combine(mv, mi, ov, oi);
        }
        scores[r] = mv; fr[r] = mi;
        #pragma unroll
        for (int t = 0; t < 4; ++t)
            if (lane * 4 + t == mi) cv[t] = -INFINITY;
    }

    // phase 3: h_r = x[n] . down_embed[fr[r]]   (wave-parallel dots)
    float xv[8];
    #pragma unroll
    for (int e = 0; e < 8; ++e) xv[e] = x[(size_t)n * NDIM + lane + e * 64];
    float hv[16];
    #pragma unroll
    for (int r = 0; r < 16; ++r) {
        const float* de = down + (size_t)fr[r] * NDIM;
        float a = 0.f;
        #pragma unroll
        for (int e = 0; e < 8; ++e) a += xv[e] * de[lane + e * 64];
        #pragma unroll
        for (int off = 1; off < 64; off <<= 1) a += __shfl_xor(a, off);
        hv[r] = a;
    }

    // phase 4: softmax(scores) * gelu_exact(h), store (idx, weight)
    const float m = scores[0];  // sorted descending -> max
    float ev[16], esum = 0.f;
    #pragma unroll
    for (int r = 0; r < 16; ++r) { ev[r] = expf(scores[r] - m); esum += ev[r]; }
    const float inv = 1.0f / esum;
    float wr[16];
    #pragma unroll
    for (int r = 0; r < 16; ++r) {
        float g = 0.5f * hv[r] * (1.0f + erff(hv[r] * 0.70710678118654752f));
        wr[r] = ev[r] * inv * g;
    }
    if (lane == 0) {
        #pragma unroll
        for (int r = 0; r < 16; ++r) {
            idx_out[(size_t)pair * 16 + r] = fr[r];
            w_out[(size_t)pair * 16 + r] = wr[r];
        }
    }
}

// ---------------- K4: out[n,:] = sum_{h,k} w * up_embed[idx]  (256 hot rows, L2-resident)
__global__ __launch_bounds__(256) void k4_out(const int* __restrict__ idx,
                                              const float* __restrict__ w,
                                              const float* __restrict__ up,
                                              float* __restrict__ out) {
    __shared__ int sidx[128];
    __shared__ float sw[128];
    const int n = blockIdx.x;
    const int tid = threadIdx.x;
    if (tid < 128) {
        sidx[tid] = idx[(size_t)n * 128 + tid];
        sw[tid] = w[(size_t)n * 128 + tid];
    }
    __syncthreads();
    const int d = tid * 2;
    float2 acc = {0.f, 0.f};
    for (int i = 0; i < 128; ++i) {
        float2 u = *reinterpret_cast<const float2*>(&up[(size_t)sidx[i] * NDIM + d]);
        acc.x += sw[i] * u.x;
        acc.y += sw[i] * u.y;
    }
    *reinterpret_cast<float2*>(&out[(size_t)n * NDIM + d]) = acc;
}

extern "C" void kernel_launch(void* const* d_in, const int* in_sizes, int n_in,
                              void* d_out, int out_size, void* d_ws, size_t ws_size,
                              hipStream_t stream) {
    const float* x    = (const float*)d_in[0];
    const float* Wq   = (const float*)d_in[1];
    const float* keys = (const float*)d_in[2];
    const float* down = (const float*)d_in[3];
    const float* up   = (const float*)d_in[4];
    float* out = (float*)d_out;

    char* ws = (char*)d_ws;
    float* M   = (float*)(ws);                                  //  8 MB: [512,4096]
    float* sim = (float*)(ws + (size_t)8 * 1024 * 1024);        // 32 MB: [2048,4096]
    int*   idx = (int*)  (ws + (size_t)40 * 1024 * 1024);       //  2 MB
    float* wgt = (float*)(ws + (size_t)42 * 1024 * 1024);       //  2 MB

    k1_combine<<<dim3(8, 4, 16), 256, 0, stream>>>(Wq, keys, M);
    k2_gemm<<<dim3(16, 32), 256, 0, stream>>>(x, M, sim);
    k3_topk<<<4096, 256, 0, stream>>>(sim, x, down, idx, wgt);
    k4_out<<<2048, 256, 0, stream>>>(idx, wgt, up, out);
}